// Round 1
// baseline (653.123 us; speedup 1.0000x reference)
//
#include <hip/hip_runtime.h>
#include <hip/hip_bf16.h>

#define H 224
#define W 224
#define C 256
#define F 256
#define OB 14

typedef __attribute__((ext_vector_type(8))) short short8;
typedef __attribute__((ext_vector_type(4))) float f32x4;

__device__ __forceinline__ unsigned short f2bf(float f) {
    union { float f; unsigned u; } v; v.f = f;
    unsigned r = v.u + 0x7fffu + ((v.u >> 16) & 1u);
    return (unsigned short)(r >> 16);
}

// ---------------------------------------------------------------------------
// Weight repack: kernel[ky][kx][c][f] fp32  ->  bf16 B-fragment-major layout
// wrep[((kt*16 + nt)*64 + lane)*8 + j] = bf16(w[kk][c32*32 + quad*8 + j][nt*16 + lq])
// kt = kk*8 + c32 (kk = ky*3+kx in [0,9), c32 in [0,8)), quad = lane>>4, lq = lane&15
// ---------------------------------------------------------------------------
__global__ __launch_bounds__(256) void repack_kernel(const float* __restrict__ wsrc,
                                                     unsigned short* __restrict__ wrep) {
    int g = blockIdx.x * 256 + threadIdx.x;   // < 72*16*64 = 73728
    int lane = g & 63;
    int nt   = (g >> 6) & 15;
    int kt   = g >> 10;
    int kk   = kt >> 3, c32 = kt & 7;
    int quad = lane >> 4, lq = lane & 15;
    int cbase = c32 * 32 + quad * 8;
    int f = nt * 16 + lq;
    alignas(16) unsigned short tmp[8];
#pragma unroll
    for (int j = 0; j < 8; ++j) {
        tmp[j] = f2bf(wsrc[((size_t)(kk * 256 + cbase + j)) * 256 + f]);
    }
    *reinterpret_cast<uint4*>(wrep + (size_t)g * 8) = *reinterpret_cast<const uint4*>(tmp);
}

// ---------------------------------------------------------------------------
// Active flags: mean of 16x16 padded mask patch > 0.5
// ---------------------------------------------------------------------------
__global__ __launch_bounds__(256) void flags_kernel(const float* __restrict__ mask,
                                                    int* __restrict__ flags) {
    int b = blockIdx.x;                 // 0..1023  (n, by, bx)
    int n = b >> 8, by = (b >> 4) & 15, bx = b & 15;
    int t = threadIdx.x;                // 256 = 16x16 patch positions
    int r = t >> 4, s = t & 15;
    int gy = by * OB - 1 + r, gx = bx * OB - 1 + s;
    float v = 0.f;
    if ((unsigned)gy < (unsigned)H && (unsigned)gx < (unsigned)W)
        v = mask[((size_t)n * H + gy) * W + gx];
    __shared__ float red[256];
    red[t] = v;
    __syncthreads();
    for (int s2 = 128; s2 > 0; s2 >>= 1) {
        if (t < s2) red[t] += red[t + s2];
        __syncthreads();
    }
    if (t == 0) flags[b] = (red[0] * (1.0f / 256.0f)) > 0.5f ? 1 : 0;
}

// ---------------------------------------------------------------------------
// Conv kernel: 1 workgroup (8 waves / 512 thr) per block.
// Inactive -> zero-fill. Active -> bf16 MFMA implicit GEMM:
//   M = 196 pixels (13 tiles of 16, padded), N = 256 (wave owns 2 x 16), K = 2304.
// Patch staged in LDS in two 128-channel chunks (64 KB).
// ---------------------------------------------------------------------------
__global__ __launch_bounds__(512) void conv_kernel(const float* __restrict__ in,
                                                   const int* __restrict__ flags,
                                                   const unsigned short* __restrict__ wrep,
                                                   const float* __restrict__ bias,
                                                   float* __restrict__ out) {
    __shared__ __align__(16) unsigned short patch[256 * 128];  // [pix 16x16][128 ch] bf16 = 64 KB

    const int b = blockIdx.x;
    const int n = b >> 8, by = (b >> 4) & 15, bx = b & 15;
    const int tid = threadIdx.x;
    float* outB = out + (size_t)n * H * W * F;

    if (!flags[b]) {
        // write zeros for this block's 14x14x256 output region
        for (int idx = tid; idx < 196 * 64; idx += 512) {
            int pix = idx >> 6, fv = idx & 63;
            int oy = pix / 14, ox = pix - oy * 14;
            size_t o = ((size_t)((by * OB + oy) * W + bx * OB + ox)) * F + fv * 4;
            *reinterpret_cast<float4*>(outB + o) = make_float4(0.f, 0.f, 0.f, 0.f);
        }
        return;
    }

    const int wave = tid >> 6, lane = tid & 63;
    const int quad = lane >> 4, lq = lane & 15;
    const int f0 = wave * 32 + lq, f1 = f0 + 16;
    const int nt0 = wave * 2;

    // Per-M-tile LDS pixel offsets for A fragments (elements, incl. quad k-offset)
    int pixoff[13];
#pragma unroll
    for (int mt = 0; mt < 13; ++mt) {
        int p = mt * 16 + lq;
        if (p > 195) p = 195;               // clamp tail tile (stores guarded later)
        int oy = p / 14, ox = p - oy * 14;
        pixoff[mt] = ((oy * 16 + ox) << 7) + (quad << 3);
    }

    f32x4 acc[13][2];
#pragma unroll
    for (int mt = 0; mt < 13; ++mt) {
        acc[mt][0] = (f32x4)(0.f);
        acc[mt][1] = (f32x4)(0.f);
    }

    const float* inB = in + (size_t)n * H * W * C;
    const int gy0 = by * OB - 1, gx0 = bx * OB - 1;

    for (int cc = 0; cc < 2; ++cc) {
        __syncthreads();  // protect patch from previous chunk's readers
        // stage 16x16 x 128ch chunk: fp32 -> bf16 into LDS
        for (int it = 0; it < 16; ++it) {
            int idx = tid + it * 512;       // 8192 float4 units
            int pix = idx >> 5, chv = idx & 31;
            int r = pix >> 4, s = pix & 15;
            int gy = gy0 + r, gx = gx0 + s;
            float4 v = make_float4(0.f, 0.f, 0.f, 0.f);
            if ((unsigned)gy < (unsigned)H && (unsigned)gx < (unsigned)W)
                v = *reinterpret_cast<const float4*>(inB + ((size_t)(gy * W + gx)) * C + cc * 128 + chv * 4);
            uint2 bb;
            bb.x = (unsigned)f2bf(v.x) | ((unsigned)f2bf(v.y) << 16);
            bb.y = (unsigned)f2bf(v.z) | ((unsigned)f2bf(v.w) << 16);
            *reinterpret_cast<uint2*>(&patch[(pix << 7) + chv * 4]) = bb;
        }
        __syncthreads();

        for (int kk = 0; kk < 9; ++kk) {
            const int ky = kk / 3, kx = kk - ky * 3;
            const int pixadd = (ky * 16 + kx) << 7;
#pragma unroll
            for (int c32l = 0; c32l < 4; ++c32l) {
                const int ktg = kk * 8 + cc * 4 + c32l;
                const size_t wo = ((size_t)(ktg * 16 + nt0) * 64 + lane) * 8;
                short8 b0 = *reinterpret_cast<const short8*>(wrep + wo);
                short8 b1 = *reinterpret_cast<const short8*>(wrep + wo + 64 * 8);
                const int koff = pixadd + c32l * 32;
#pragma unroll
                for (int mt = 0; mt < 13; ++mt) {
                    short8 a = *reinterpret_cast<const short8*>(&patch[pixoff[mt] + koff]);
                    acc[mt][0] = __builtin_amdgcn_mfma_f32_16x16x32_bf16(a, b0, acc[mt][0], 0, 0, 0);
                    acc[mt][1] = __builtin_amdgcn_mfma_f32_16x16x32_bf16(a, b1, acc[mt][1], 0, 0, 0);
                }
            }
        }
    }

    // Epilogue: bias + relu + store. D layout: col = lane&15, row = quad*4 + reg.
    const float bv0 = bias[f0], bv1 = bias[f1];
#pragma unroll
    for (int mt = 0; mt < 13; ++mt) {
#pragma unroll
        for (int j = 0; j < 4; ++j) {
            int p = mt * 16 + quad * 4 + j;
            if (p < 196) {
                int oy = p / 14, ox = p - oy * 14;
                size_t o = ((size_t)((by * OB + oy) * W + bx * OB + ox)) * F;
                float v0 = acc[mt][0][j] + bv0;
                float v1 = acc[mt][1][j] + bv1;
                outB[o + f0] = v0 > 0.f ? v0 : 0.f;
                outB[o + f1] = v1 > 0.f ? v1 : 0.f;
            }
        }
    }
}

extern "C" void kernel_launch(void* const* d_in, const int* in_sizes, int n_in,
                              void* d_out, int out_size, void* d_ws, size_t ws_size,
                              hipStream_t stream) {
    const float* inputs = (const float*)d_in[0];
    const float* mask   = (const float*)d_in[1];
    const float* wsrc   = (const float*)d_in[2];
    const float* bias   = (const float*)d_in[3];
    float* outp = (float*)d_out;

    int* flags = (int*)d_ws;                                    // 1024 ints
    unsigned short* wrep = (unsigned short*)((char*)d_ws + 4096); // 72*16*64*8 bf16 = 1.18 MB

    hipLaunchKernelGGL(repack_kernel, dim3(288), dim3(256), 0, stream, wsrc, wrep);
    hipLaunchKernelGGL(flags_kernel, dim3(1024), dim3(256), 0, stream, mask, flags);
    hipLaunchKernelGGL(conv_kernel, dim3(1024), dim3(512), 0, stream, inputs, flags, wrep, bias, outp);
}